// Round 10
// baseline (1164.713 us; speedup 1.0000x reference)
//
#include <hip/hip_runtime.h>
#include <math.h>

#define B 32
#define S 4096
#define N 1024
#define L2E 1.4426950408889634f

typedef short short8 __attribute__((ext_vector_type(8)));
typedef short short4v __attribute__((ext_vector_type(4)));
typedef float float4v __attribute__((ext_vector_type(4)));

__device__ inline short f2bf(float f) {
    unsigned u = __builtin_bit_cast(unsigned, f);
    u += 0x7fffu + ((u >> 16) & 1u);   // RNE
    return (short)(u >> 16);
}

// async global->LDS DMA, 16 B per lane. LDS dest wave-uniform + lane*16 linear.
__device__ __forceinline__ void load_lds16(const void* g, void* l) {
    __builtin_amdgcn_global_load_lds(
        (const __attribute__((address_space(1))) void*)g,
        (__attribute__((address_space(3))) void*)l, 16, 0, 0);
}

// ---------------------------------------------------------------------------
// Kernel 1 (fast path): fused front-end.
//   blocks [0,2048):    cvt enc fp32->bf16; blocks [0,512) also zero e[B*S].
//   blocks [2048,2064):  cvt Wh fp32->bf16.
//   blocks [2064,10256): dec_feats, one wave per (b,m), coalesced + shuffle.
// ---------------------------------------------------------------------------
__global__ __launch_bounds__(256)
void prep_cvt_kernel(const float* __restrict__ dec, const float* __restrict__ Ws,
                     const float* __restrict__ bs, const float* __restrict__ enc,
                     const float* __restrict__ Wh, float* __restrict__ dec_feats,
                     float* __restrict__ e, short* __restrict__ encb,
                     short* __restrict__ whb) {
    unsigned bid = blockIdx.x;
    int tid = threadIdx.x;
    if (bid < 2048u) {
        if (bid < 512u) e[bid * 256 + tid] = 0.f;
        const size_t n8e = (size_t)B * S * N / 8;
        for (size_t i = (size_t)bid * 256 + tid; i < n8e; i += 2048u * 256u) {
            const float4v* s = (const float4v*)(enc + i * 8);
            float4v a = s[0], b = s[1];
            short8 o = { f2bf(a.x), f2bf(a.y), f2bf(a.z), f2bf(a.w),
                         f2bf(b.x), f2bf(b.y), f2bf(b.z), f2bf(b.w) };
            *(short8*)(encb + i * 8) = o;
        }
    } else if (bid < 2064u) {
        const size_t n8w = (size_t)N * N / 8;
        for (size_t i = (size_t)(bid - 2048u) * 256 + tid; i < n8w; i += 16u * 256u) {
            const float4v* s = (const float4v*)(Wh + i * 8);
            float4v a = s[0], b = s[1];
            short8 o = { f2bf(a.x), f2bf(a.y), f2bf(a.z), f2bf(a.w),
                         f2bf(b.x), f2bf(b.y), f2bf(b.z), f2bf(b.w) };
            *(short8*)(whb + i * 8) = o;
        }
    } else {
        int wid  = (int)(bid - 2064u) * 4 + (tid >> 6);  // 0..32767 = (m,b)
        int lane = tid & 63;
        int m = wid >> 5, b = wid & 31;
        const float4* drow = (const float4*)(dec + (size_t)b * N);
        const float4* wrow = (const float4*)(Ws + (size_t)m * N);
        float acc = 0.f;
#pragma unroll
        for (int k = 0; k < 4; ++k) {
            float4 a = drow[lane + (k << 6)];
            float4 w = wrow[lane + (k << 6)];
            acc += a.x * w.x + a.y * w.y + a.z * w.z + a.w * w.w;
        }
        acc += __shfl_xor(acc, 1);  acc += __shfl_xor(acc, 2);
        acc += __shfl_xor(acc, 4);  acc += __shfl_xor(acc, 8);
        acc += __shfl_xor(acc, 16); acc += __shfl_xor(acc, 32);
        if (lane == 0) dec_feats[(size_t)b * N + m] = acc + bs[m];
    }
}

// ---------------------------------------------------------------------------
// Kernel 1b (fallback path): zero(e) + dec_feats only.
// ---------------------------------------------------------------------------
__global__ __launch_bounds__(256)
void prep_kernel(const float* __restrict__ dec, const float* __restrict__ Ws,
                 const float* __restrict__ bs, float* __restrict__ dec_feats,
                 float* __restrict__ e) {
    int tg = blockIdx.x * 256 + threadIdx.x;
    if (tg < B * S) e[tg] = 0.f;
    int wid  = (blockIdx.x << 2) + (threadIdx.x >> 6);
    int lane = threadIdx.x & 63;
    int m = wid >> 5, b = wid & 31;
    const float4* drow = (const float4*)(dec + (size_t)b * N);
    const float4* wrow = (const float4*)(Ws + (size_t)m * N);
    float acc = 0.f;
#pragma unroll
    for (int k = 0; k < 4; ++k) {
        float4 a = drow[lane + (k << 6)];
        float4 w = wrow[lane + (k << 6)];
        acc += a.x * w.x + a.y * w.y + a.z * w.z + a.w * w.w;
    }
    acc += __shfl_xor(acc, 1);  acc += __shfl_xor(acc, 2);
    acc += __shfl_xor(acc, 4);  acc += __shfl_xor(acc, 8);
    acc += __shfl_xor(acc, 16); acc += __shfl_xor(acc, 32);
    if (lane == 0) dec_feats[(size_t)b * N + m] = acc + bs[m];
}

// ---------------------------------------------------------------------------
// Kernel 2a: 256x256 8-phase bf16 MFMA GEMM (T1+T2+T3+T4+T5), fused tanh·v
// epilogue. Inner schedule chip-verified (r4-r8: conflicts 0, absmax 0.0039).
// r8: FOUR row-tiles per block (fixed m-tile), grid 512 = 2 CU-rounds.
// Quads never straddle batches (4 | 16 tiles/batch) -> basej hoist valid.
// Seam per tile: epilogue atomics increment vmcnt -> drain vmcnt(0) + barrier
// before next tile's prologue.
// ---------------------------------------------------------------------------
#define REGION_A(slot, hk) ((slot)*16384 + (hk)*8192)
#define REGION_B(slot, hk) (32768 + (slot)*16384 + (hk)*8192)

__global__ __launch_bounds__(512, 2)
void score_mfma8_kernel(const short* __restrict__ encb, const short* __restrict__ whb,
                        const float* __restrict__ bh, const float* __restrict__ dec_feats,
                        const float* __restrict__ cov, const float* __restrict__ wc,
                        const float* __restrict__ v, float* __restrict__ e) {
    __shared__ short lds[65536];   // 128 KiB

    // T1: bijective XCD swizzle (512 = 8 * 64). Consecutive c on one XCD
    // cycle 4 m-tiles over the same row-quad: A-quad (2MB) + whb (2MB)
    // L2-resident.
    unsigned bid = blockIdx.x;
    unsigned c = (bid & 7u) * 64u + (bid >> 3);
    int rtq = (int)(c >> 2), mtile = (int)(c & 3u);
    int m0 = mtile * 256;

    int t = threadIdx.x, lane = t & 63, w = t >> 6;
    int wm_ = w >> 2, wn_ = w & 3;         // 2 x 4 wave grid
    int cq = lane >> 4, cm = lane & 15;

    int srow = lane >> 2;                              // 0..15 within chunk
    int sg = (lane & 3) ^ ((lane >> 3) & 3);           // logical granule
    const short* bS0 = whb + (size_t)(m0 + w * 16 + srow) * N + sg * 8;
    const short* bS1 = bS0 + (size_t)128 * N;
    const int dc0 = w * 512, dc1 = dc0 + 4096;         // chunk dests (shorts)

    int aoff[8], boff[4];
#pragma unroll
    for (int f = 0; f < 8; ++f) {
        int R = wm_ * 128 + f * 16 + cm;
        aoff[f] = R * 32 + ((cq ^ ((R >> 1) & 3)) << 3);
    }
#pragma unroll
    for (int j = 0; j < 4; ++j) {
        int R = wn_ * 64 + j * 16 + cm;
        boff[j] = R * 32 + ((cq ^ ((R >> 1) & 3)) << 3);
    }

    float basej[4], wcj[4], vj[4];   // m-side constants: invariant across tiles
    {
        int bidx0 = rtq >> 2;        // batch of all 4 tiles in this quad
        const float* df = dec_feats + ((size_t)bidx0 << 10);
#pragma unroll
        for (int j = 0; j < 4; ++j) {
            int m = m0 + wn_ * 64 + j * 16 + cm;
            basej[j] = bh[m] + df[m];
            wcj[j]   = wc[m];
            vj[j]    = v[m];
        }
    }

#define STAGE(srcp0, srcp1, region, colElem) do {                         \
        int _cc = (colElem) & (N - 1);                                    \
        load_lds16((srcp0) + _cc, &lds[(region) + dc0]);                  \
        load_lds16((srcp1) + _cc, &lds[(region) + dc1]);                  \
    } while (0)

#define PHASE(slot, sub, SRC0, SRC1, SREGION, SCOL) do {                      \
        const int hk_ = (sub) >> 1, mh_ = (sub) & 1;                          \
        if (mh_ == 0) {                                                       \
            _Pragma("unroll")                                                 \
            for (int j = 0; j < 4; ++j)                                       \
                bf[j] = *(const short8*)&lds[REGION_B(slot, hk_) + boff[j]];  \
        }                                                                     \
        short8 af[4];                                                         \
        _Pragma("unroll")                                                     \
        for (int f = 0; f < 4; ++f)                                           \
            af[f] = *(const short8*)&lds[REGION_A(slot, hk_) + aoff[mh_ * 4 + f]]; \
        STAGE(SRC0, SRC1, SREGION, SCOL);                                     \
        __builtin_amdgcn_s_barrier();                                         \
        asm volatile("s_waitcnt lgkmcnt(0)" ::: "memory");                    \
        __builtin_amdgcn_sched_barrier(0);                                    \
        __builtin_amdgcn_s_setprio(1);                                        \
        _Pragma("unroll")                                                     \
        for (int f = 0; f < 4; ++f)                                           \
            _Pragma("unroll")                                                 \
            for (int j = 0; j < 4; ++j)                                       \
                acc[mh_ * 4 + f][j] = __builtin_amdgcn_mfma_f32_16x16x32_bf16(\
                    af[f], bf[j], acc[mh_ * 4 + f][j], 0, 0, 0);              \
        __builtin_amdgcn_s_setprio(0);                                        \
        if (mh_ == 1) asm volatile("s_waitcnt vmcnt(8)" ::: "memory");        \
        __builtin_amdgcn_s_barrier();                                         \
    } while (0)

#pragma unroll 1
    for (int it = 0; it < 4; ++it) {
        int r0 = (rtq * 4 + it) * 256;
        const short* aS0 = encb + (size_t)(r0 + w * 16 + srow) * N + sg * 8;
        const short* aS1 = aS0 + (size_t)128 * N;

        float4v acc[8][4];
#pragma unroll
        for (int f = 0; f < 8; ++f)
#pragma unroll
            for (int j = 0; j < 4; ++j) acc[f][j] = (float4v){0.f, 0.f, 0.f, 0.f};

        // Prologue: kt0 (slot0 both halves) + kt1 half0 (slot1). 12 loads.
        STAGE(aS0, aS1, REGION_A(0, 0), 0);
        STAGE(bS0, bS1, REGION_B(0, 0), 0);
        STAGE(aS0, aS1, REGION_A(0, 1), 32);
        STAGE(bS0, bS1, REGION_B(0, 1), 32);
        STAGE(aS0, aS1, REGION_A(1, 0), 64);
        STAGE(bS0, bS1, REGION_B(1, 0), 64);
        asm volatile("s_waitcnt vmcnt(8)" ::: "memory");   // slot0 h0 done
        __builtin_amdgcn_s_barrier();

        short8 bf[4];

#pragma unroll 1
        for (int i = 0; i < 8; ++i) {        // 8 iters x 2 K-tiles = K=1024
            int kb = i * 128;
            PHASE(0, 0, aS0, aS1, REGION_A(1, 1), kb + 96);
            PHASE(0, 1, bS0, bS1, REGION_B(1, 1), kb + 96);
            PHASE(0, 2, aS0, aS1, REGION_A(0, 0), kb + 128);
            PHASE(0, 3, bS0, bS1, REGION_B(0, 0), kb + 128);
            PHASE(1, 0, aS0, aS1, REGION_A(0, 1), kb + 160);
            PHASE(1, 1, bS0, bS1, REGION_B(0, 1), kb + 160);
            PHASE(1, 2, aS0, aS1, REGION_A(1, 0), kb + 192);
            PHASE(1, 3, bS0, bS1, REGION_B(1, 0), kb + 192);
        }
        asm volatile("s_waitcnt vmcnt(0)" ::: "memory");

        // Epilogue. tanh(x) = 1 - 2/(exp2(2*log2e*x)+1).
#pragma unroll
        for (int f = 0; f < 8; ++f) {
            int rbase = r0 + wm_ * 128 + f * 16 + cq * 4;
            float4v cvv = *(const float4v*)&cov[rbase];
            float cv[4] = {cvv.x, cvv.y, cvv.z, cvv.w};
            float rs[4] = {0.f, 0.f, 0.f, 0.f};
#pragma unroll
            for (int j = 0; j < 4; ++j) {
#pragma unroll
                for (int reg = 0; reg < 4; ++reg) {
                    float val = acc[f][j][reg] + basej[j] + cv[reg] * wcj[j];
                    val = fminf(fmaxf(val, -15.f), 15.f);
                    float t2 = __builtin_amdgcn_exp2f(val * 2.8853900817779268f);
                    float r  = __builtin_amdgcn_rcpf(t2 + 1.f);
                    float th = fmaf(-2.f, r, 1.f);
                    rs[reg] = fmaf(th, vj[j], rs[reg]);
                }
            }
#pragma unroll
            for (int reg = 0; reg < 4; ++reg) {
                float p = rs[reg];
                p += __shfl_xor(p, 1);
                p += __shfl_xor(p, 2);
                p += __shfl_xor(p, 4);
                p += __shfl_xor(p, 8);
                if (cm == 0) atomicAdd(&e[rbase + reg], p);   // same-XCD (T1)
            }
        }
        // Seam: drain epilogue atomics from vmcnt so next prologue's
        // vmcnt(8) counts only its own 12 loads; align waves.
        asm volatile("s_waitcnt vmcnt(0)" ::: "memory");
        __builtin_amdgcn_s_barrier();
    }
#undef PHASE
#undef STAGE
}

// ---------------------------------------------------------------------------
// Kernel 2b (fallback if workspace too small): fp32-staging MFMA kernel.
// ---------------------------------------------------------------------------
#define BR 128
#define BM 128
#define BK 64
#define LDK (BK + 8)

__global__ __launch_bounds__(256)
void score_mfma_kernel(const float* __restrict__ enc, const float* __restrict__ Wh,
                       const float* __restrict__ bh, const float* __restrict__ dec_feats,
                       const float* __restrict__ cov, const float* __restrict__ wc,
                       const float* __restrict__ v, float* __restrict__ e) {
    __shared__ short As[BR][LDK];
    __shared__ short Bs[BM][LDK];

    unsigned h   = blockIdx.x;
    unsigned xcd = h & 7u;
    unsigned mt  = (h >> 3) & 7u;
    unsigned g   = h >> 6;
    int r0 = (int)(xcd + 8u * g) * BR;
    int m0 = (int)mt * BM;

    int t    = threadIdx.x;
    int lane = t & 63;
    int w    = t >> 6;
    int wr   = (w >> 1) * 64;
    int wm   = (w & 1) * 64;
    int cq   = lane >> 4;
    int cm   = lane & 15;

    float4v acc[4][4];
#pragma unroll
    for (int i = 0; i < 4; ++i)
#pragma unroll
        for (int j = 0; j < 4; ++j) acc[i][j] = (float4v){0.f, 0.f, 0.f, 0.f};

    int srow = t >> 4;
    int scol = (t & 15) * 4;

    for (int k0 = 0; k0 < N; k0 += BK) {
#pragma unroll
        for (int p = 0; p < 8; ++p) {
            int row = p * 16 + srow;
            float4v a = *(const float4v*)(enc + (size_t)(r0 + row) * N + k0 + scol);
            short4v ap = { f2bf(a.x), f2bf(a.y), f2bf(a.z), f2bf(a.w) };
            *(short4v*)&As[row][scol] = ap;
            float4v bq = *(const float4v*)(Wh + (size_t)(m0 + row) * N + k0 + scol);
            short4v bp = { f2bf(bq.x), f2bf(bq.y), f2bf(bq.z), f2bf(bq.w) };
            *(short4v*)&Bs[row][scol] = bp;
        }
        __syncthreads();
#pragma unroll
        for (int ks = 0; ks < BK; ks += 32) {
            short8 af[4], bfr[4];
#pragma unroll
            for (int i = 0; i < 4; ++i)
                af[i] = *(const short8*)&As[wr + i * 16 + cm][ks + cq * 8];
#pragma unroll
            for (int j = 0; j < 4; ++j)
                bfr[j] = *(const short8*)&Bs[wm + j * 16 + cm][ks + cq * 8];
#pragma unroll
            for (int i = 0; i < 4; ++i)
#pragma unroll
                for (int j = 0; j < 4; ++j)
                    acc[i][j] = __builtin_amdgcn_mfma_f32_16x16x32_bf16(
                        af[i], bfr[j], acc[i][j], 0, 0, 0);
        }
        __syncthreads();
    }

    int b = r0 >> 12;
    const float* df = dec_feats + ((size_t)b << 10);

    float basej[4], wcj[4], vj[4];
#pragma unroll
    for (int j = 0; j < 4; ++j) {
        int m = m0 + wm + j * 16 + cm;
        basej[j] = bh[m] + df[m];
        wcj[j]   = wc[m];
        vj[j]    = v[m];
    }

#pragma unroll
    for (int i = 0; i < 4; ++i) {
        int rbase = r0 + wr + i * 16 + cq * 4;
        float cv[4];
#pragma unroll
        for (int reg = 0; reg < 4; ++reg) cv[reg] = cov[rbase + reg];
        float rs[4] = {0.f, 0.f, 0.f, 0.f};
#pragma unroll
        for (int j = 0; j < 4; ++j) {
#pragma unroll
            for (int reg = 0; reg < 4; ++reg) {
                float val = acc[i][j][reg] + basej[j] + cv[reg] * wcj[j];
                val = fminf(fmaxf(val, -15.f), 15.f);
                float t2 = __builtin_amdgcn_exp2f(val * 2.8853900817779268f);
                float r  = __builtin_amdgcn_rcpf(t2 + 1.f);
                float th = fmaf(-2.f, r, 1.f);
                rs[reg] = fmaf(th, vj[j], rs[reg]);
            }
        }
#pragma unroll
        for (int reg = 0; reg < 4; ++reg) {
            float p = rs[reg];
            p += __shfl_xor(p, 1);
            p += __shfl_xor(p, 2);
            p += __shfl_xor(p, 4);
            p += __shfl_xor(p, 8);
            if (cm == 0) atomicAdd(&e[rbase + reg], p);
        }
    }
}

// ---------------------------------------------------------------------------
// Kernel 3a (fast path): per-chunk masked softmax partials.
// Block (ch, b): 512 e-values -> (max, sum_exp) pair. NaN-guarded for
// fully-masked chunks (pair = (-inf, 0) combines correctly downstream).
// ---------------------------------------------------------------------------
__global__ __launch_bounds__(256)
void softmax_partial_kernel(const float* __restrict__ e, const int* __restrict__ lens,
                            float2* __restrict__ pm) {
    int b = blockIdx.y, ch = blockIdx.x;   // ch 0..7
    int t = threadIdx.x, lane = t & 63, wid = t >> 6;
    int len = lens[b];
    int s0 = ch * 512;
    const float* eb = e + (size_t)b * S + s0;
    float v0 = (s0 + t       < len) ? eb[t]       : -INFINITY;
    float v1 = (s0 + t + 256 < len) ? eb[t + 256] : -INFINITY;
    float mx = fmaxf(v0, v1);
    mx = fmaxf(mx, __shfl_xor(mx, 1));  mx = fmaxf(mx, __shfl_xor(mx, 2));
    mx = fmaxf(mx, __shfl_xor(mx, 4));  mx = fmaxf(mx, __shfl_xor(mx, 8));
    mx = fmaxf(mx, __shfl_xor(mx, 16)); mx = fmaxf(mx, __shfl_xor(mx, 32));
    __shared__ float redm[4], reds[4];
    if (lane == 0) redm[wid] = mx;
    __syncthreads();
    mx = fmaxf(fmaxf(redm[0], redm[1]), fmaxf(redm[2], redm[3]));

    float sum = 0.f;
    if (mx > -INFINITY)   // guard: fully-masked chunk -> (-inf - -inf) = NaN
        sum = exp2f((v0 - mx) * L2E) + exp2f((v1 - mx) * L2E);
    sum += __shfl_xor(sum, 1);  sum += __shfl_xor(sum, 2);
    sum += __shfl_xor(sum, 4);  sum += __shfl_xor(sum, 8);
    sum += __shfl_xor(sum, 16); sum += __shfl_xor(sum, 32);
    if (lane == 0) reds[wid] = sum;
    __syncthreads();
    if (t == 0) {
        float2 p; p.x = mx; p.y = reds[0] + reds[1] + reds[2] + reds[3];
        pm[b * 8 + ch] = p;
    }
}

// ---------------------------------------------------------------------------
// Kernel 4 (fast path): fused softmax-finalize + attn/cov_out write + context
// partial. Block (ch, b) combines the 8 (m,s) pairs (logsumexp merge; exact
// same attn formula as before), computes a[s] for its 64-s chunk (in LDS),
// writes attn & cov_out, then accumulates context partial from fp32 enc
// (bf16 deliberately avoided for ctx precision).
// ---------------------------------------------------------------------------
#define SCH 64
__global__ __launch_bounds__(256)
void context_part_kernel(const float* __restrict__ e, const int* __restrict__ lens,
                         const float2* __restrict__ pm, const float* __restrict__ cov,
                         const float* __restrict__ enc, float* __restrict__ attn,
                         float* __restrict__ cov_out, float* __restrict__ part) {
    int b  = blockIdx.y;
    int ch = blockIdx.x;
    int s0 = ch * (S / SCH);       // 64 s per block
    int tid = threadIdx.x;
    __shared__ float a_lds[S / SCH];

    if (tid < S / SCH) {
        int len = lens[b];
        const float2* pb = pm + b * 8;
        float M = -INFINITY;
#pragma unroll
        for (int i = 0; i < 8; ++i) M = fmaxf(M, pb[i].x);
        float Ssum = 0.f;
#pragma unroll
        for (int i = 0; i < 8; ++i)    // (-inf,0) pairs: 0 * exp2(-inf)=0 ok
            Ssum += pb[i].y * exp2f((pb[i].x - M) * L2E);
        float inv = 1.f / Ssum;
        int s = s0 + tid;
        float ew = e[(size_t)b * S + s];
        float a = (s < len) ? exp2f((ew - M) * L2E) * inv : 0.f;
        a_lds[tid] = a;
        attn[(size_t)b * S + s] = a;
        cov_out[(size_t)b * S + s] = cov[(size_t)b * S + s] + a;
    }
    __syncthreads();

    const float4* ep = (const float4*)(enc + ((size_t)b * S + s0) * N);
    float4 acc = {0.f, 0.f, 0.f, 0.f};
    for (int s = 0; s < S / SCH; ++s) {
        float a = a_lds[s];
        float4 ev = ep[(size_t)s * (N / 4) + tid];
        acc.x += a * ev.x; acc.y += a * ev.y;
        acc.z += a * ev.z; acc.w += a * ev.w;
    }
    *(float4*)&part[((size_t)b * SCH + ch) * N + tid * 4] = acc;
}

__global__ __launch_bounds__(256)
void context_reduce_kernel(const float* __restrict__ part, float* __restrict__ ctx) {
    int idx = blockIdx.x * 256 + threadIdx.x;   // 0 .. B*N-1
    int b = idx >> 10, n = idx & (N - 1);
    const float* p = part + (size_t)b * SCH * N + n;
    float acc = 0.f;
#pragma unroll
    for (int c2 = 0; c2 < SCH; ++c2) acc += p[(size_t)c2 * N];
    ctx[idx] = acc;
}

// ---------------------------------------------------------------------------
// Fallback helpers: monolithic softmax + atomic context (need ctx pre-zeroed).
// ---------------------------------------------------------------------------
__global__ __launch_bounds__(1024)
void softmax_kernel(const float* __restrict__ e, const int* __restrict__ lens,
                    const float* __restrict__ cov,
                    float* __restrict__ attn, float* __restrict__ cov_out) {
    int b = blockIdx.x, t = threadIdx.x;
    int lane = t & 63, wid = t >> 6;
    int len = lens[b];
    const float* eb = e + (size_t)b * S;
    __shared__ float redm[16], reds[16];

    float ev[4];
    float mx = -INFINITY;
#pragma unroll
    for (int k = 0; k < 4; ++k) {
        int s = t + (k << 10);
        ev[k] = (s < len) ? eb[s] : -INFINITY;
        mx = fmaxf(mx, ev[k]);
    }
    mx = fmaxf(mx, __shfl_xor(mx, 1));  mx = fmaxf(mx, __shfl_xor(mx, 2));
    mx = fmaxf(mx, __shfl_xor(mx, 4));  mx = fmaxf(mx, __shfl_xor(mx, 8));
    mx = fmaxf(mx, __shfl_xor(mx, 16)); mx = fmaxf(mx, __shfl_xor(mx, 32));
    if (lane == 0) redm[wid] = mx;
    __syncthreads();
    if (t < 16) {
        float v2 = redm[t];
        v2 = fmaxf(v2, __shfl_xor(v2, 1)); v2 = fmaxf(v2, __shfl_xor(v2, 2));
        v2 = fmaxf(v2, __shfl_xor(v2, 4)); v2 = fmaxf(v2, __shfl_xor(v2, 8));
        if (t == 0) redm[0] = v2;
    }
    __syncthreads();
    mx = redm[0];

    float ex[4];
    float sum = 0.f;
#pragma unroll
    for (int k = 0; k < 4; ++k) {
        int s = t + (k << 10);
        ex[k] = exp2f((ev[k] - mx) * L2E);
        sum += ex[k];
    }
    sum += __shfl_xor(sum, 1);  sum += __shfl_xor(sum, 2);
    sum += __shfl_xor(sum, 4);  sum += __shfl_xor(sum, 8);
    sum += __shfl_xor(sum, 16); sum += __shfl_xor(sum, 32);
    if (lane == 0) reds[wid] = sum;
    __syncthreads();
    if (t < 16) {
        float v2 = reds[t];
        v2 += __shfl_xor(v2, 1); v2 += __shfl_xor(v2, 2);
        v2 += __shfl_xor(v2, 4); v2 += __shfl_xor(v2, 8);
        if (t == 0) reds[0] = v2;
    }
    __syncthreads();
    float inv = 1.f / reds[0];

#pragma unroll
    for (int k = 0; k < 4; ++k) {
        int s = t + (k << 10);
        float a = ex[k] * inv;
        attn[(size_t)b * S + s] = a;
        cov_out[(size_t)b * S + s] = cov[(size_t)b * S + s] + a;
    }
}

__global__ __launch_bounds__(256)
void context_kernel(const float* __restrict__ attn, const float* __restrict__ enc,
                    float* __restrict__ ctx) {
    int b  = blockIdx.y;
    int s0 = blockIdx.x * (S / SCH);
    int n4 = threadIdx.x;
    const float4* ep = (const float4*)(enc + ((size_t)b * S + s0) * N);
    float4 acc = {0.f, 0.f, 0.f, 0.f};
    for (int s = 0; s < S / SCH; ++s) {
        float a = attn[(size_t)b * S + s0 + s];
        float4 ev = ep[(size_t)s * (N / 4) + n4];
        acc.x += a * ev.x; acc.y += a * ev.y;
        acc.z += a * ev.z; acc.w += a * ev.w;
    }
    float* cp = ctx + (size_t)b * N + n4 * 4;
    atomicAdd(cp + 0, acc.x);
    atomicAdd(cp + 1, acc.y);
    atomicAdd(cp + 2, acc.z);
    atomicAdd(cp + 3, acc.w);
}

// ---------------------------------------------------------------------------
extern "C" void kernel_launch(void* const* d_in, const int* in_sizes, int n_in,
                              void* d_out, int out_size, void* d_ws, size_t ws_size,
                              hipStream_t stream) {
    const float* dec  = (const float*)d_in[0];
    const float* enc  = (const float*)d_in[1];
    const int*   lens = (const int*)  d_in[2];
    const float* cov  = (const float*)d_in[3];
    const float* Wh   = (const float*)d_in[4];
    const float* bh   = (const float*)d_in[5];
    const float* Ws   = (const float*)d_in[6];
    const float* bs   = (const float*)d_in[7];
    const float* wc   = (const float*)d_in[8];
    const float* v    = (const float*)d_in[9];

    float* out     = (float*)d_out;
    float* ctx     = out;                    // B*N
    float* attn    = out + (size_t)B * N;    // B*S
    float* cov_out = attn + (size_t)B * S;   // B*S

    size_t off_e    = (size_t)B * N * 4;
    size_t off_encb = off_e + (size_t)B * S * 4;
    size_t off_whb  = off_encb + (size_t)B * S * N * 2;
    size_t off_part = off_whb + (size_t)N * N * 2;
    size_t off_pm   = off_part + (size_t)B * SCH * N * 4;
    size_t need     = off_pm + (size_t)B * 8 * sizeof(float2);

    float* dec_feats = (float*)d_ws;
    float* e         = (float*)((char*)d_ws + off_e);

    if (ws_size >= need) {
        short*  encb = (short*)((char*)d_ws + off_encb);
        short*  whb  = (short*)((char*)d_ws + off_whb);
        float*  part = (float*)((char*)d_ws + off_part);
        float2* pm   = (float2*)((char*)d_ws + off_pm);
        prep_cvt_kernel<<<10256, 256, 0, stream>>>(dec, Ws, bs, enc, Wh,
                                                   dec_feats, e, encb, whb);
        score_mfma8_kernel<<<512, 512, 0, stream>>>(
            encb, whb, bh, dec_feats, cov, wc, v, e);
        softmax_partial_kernel<<<dim3(8, B), 256, 0, stream>>>(e, lens, pm);
        context_part_kernel<<<dim3(SCH, B), 256, 0, stream>>>(
            e, lens, pm, cov, enc, attn, cov_out, part);
        context_reduce_kernel<<<(B * N) / 256, 256, 0, stream>>>(part, ctx);
    } else {
        prep_kernel<<<8192, 256, 0, stream>>>(dec, Ws, bs, dec_feats, e);
        hipMemsetAsync(ctx, 0, (size_t)B * N * sizeof(float), stream);
        score_mfma_kernel<<<(B * S / BR) * (N / BM), 256, 0, stream>>>(
            enc, Wh, bh, dec_feats, cov, wc, v, e);
        softmax_kernel<<<B, 1024, 0, stream>>>(e, lens, cov, attn, cov_out);
        context_kernel<<<dim3(SCH, B), 256, 0, stream>>>(attn, enc, ctx);
    }
}

// Round 11
// 1123.894 us; speedup vs baseline: 1.0363x; 1.0363x over previous
//
#include <hip/hip_runtime.h>
#include <math.h>

#define B 32
#define S 4096
#define N 1024
#define L2E 1.4426950408889634f

typedef short short8 __attribute__((ext_vector_type(8)));
typedef short short4v __attribute__((ext_vector_type(4)));
typedef float float4v __attribute__((ext_vector_type(4)));

__device__ inline short f2bf(float f) {
    unsigned u = __builtin_bit_cast(unsigned, f);
    u += 0x7fffu + ((u >> 16) & 1u);   // RNE
    return (short)(u >> 16);
}

// async global->LDS DMA, 16 B per lane. LDS dest wave-uniform + lane*16 linear.
__device__ __forceinline__ void load_lds16(const void* g, void* l) {
    __builtin_amdgcn_global_load_lds(
        (const __attribute__((address_space(1))) void*)g,
        (__attribute__((address_space(3))) void*)l, 16, 0, 0);
}

// ---------------------------------------------------------------------------
// Kernel 1 (fast path): fused front-end. (e-zeroing REMOVED: score now plain-
// stores e.)
//   blocks [0,2048):    cvt enc fp32->bf16.
//   blocks [2048,2064):  cvt Wh fp32->bf16.
//   blocks [2064,10256): dec_feats, one wave per (b,m), coalesced + shuffle.
// ---------------------------------------------------------------------------
__global__ __launch_bounds__(256)
void prep_cvt_kernel(const float* __restrict__ dec, const float* __restrict__ Ws,
                     const float* __restrict__ bs, const float* __restrict__ enc,
                     const float* __restrict__ Wh, float* __restrict__ dec_feats,
                     short* __restrict__ encb, short* __restrict__ whb) {
    unsigned bid = blockIdx.x;
    int tid = threadIdx.x;
    if (bid < 2048u) {
        const size_t n8e = (size_t)B * S * N / 8;
        for (size_t i = (size_t)bid * 256 + tid; i < n8e; i += 2048u * 256u) {
            const float4v* s = (const float4v*)(enc + i * 8);
            float4v a = s[0], b = s[1];
            short8 o = { f2bf(a.x), f2bf(a.y), f2bf(a.z), f2bf(a.w),
                         f2bf(b.x), f2bf(b.y), f2bf(b.z), f2bf(b.w) };
            *(short8*)(encb + i * 8) = o;
        }
    } else if (bid < 2064u) {
        const size_t n8w = (size_t)N * N / 8;
        for (size_t i = (size_t)(bid - 2048u) * 256 + tid; i < n8w; i += 16u * 256u) {
            const float4v* s = (const float4v*)(Wh + i * 8);
            float4v a = s[0], b = s[1];
            short8 o = { f2bf(a.x), f2bf(a.y), f2bf(a.z), f2bf(a.w),
                         f2bf(b.x), f2bf(b.y), f2bf(b.z), f2bf(b.w) };
            *(short8*)(whb + i * 8) = o;
        }
    } else {
        int wid  = (int)(bid - 2064u) * 4 + (tid >> 6);  // 0..32767 = (m,b)
        int lane = tid & 63;
        int m = wid >> 5, b = wid & 31;
        const float4* drow = (const float4*)(dec + (size_t)b * N);
        const float4* wrow = (const float4*)(Ws + (size_t)m * N);
        float acc = 0.f;
#pragma unroll
        for (int k = 0; k < 4; ++k) {
            float4 a = drow[lane + (k << 6)];
            float4 w = wrow[lane + (k << 6)];
            acc += a.x * w.x + a.y * w.y + a.z * w.z + a.w * w.w;
        }
        acc += __shfl_xor(acc, 1);  acc += __shfl_xor(acc, 2);
        acc += __shfl_xor(acc, 4);  acc += __shfl_xor(acc, 8);
        acc += __shfl_xor(acc, 16); acc += __shfl_xor(acc, 32);
        if (lane == 0) dec_feats[(size_t)b * N + m] = acc + bs[m];
    }
}

// ---------------------------------------------------------------------------
// Kernel 1b (fallback path): zero(e) + dec_feats only.
// ---------------------------------------------------------------------------
__global__ __launch_bounds__(256)
void prep_kernel(const float* __restrict__ dec, const float* __restrict__ Ws,
                 const float* __restrict__ bs, float* __restrict__ dec_feats,
                 float* __restrict__ e) {
    int tg = blockIdx.x * 256 + threadIdx.x;
    if (tg < B * S) e[tg] = 0.f;
    int wid  = (blockIdx.x << 2) + (threadIdx.x >> 6);
    int lane = threadIdx.x & 63;
    int m = wid >> 5, b = wid & 31;
    const float4* drow = (const float4*)(dec + (size_t)b * N);
    const float4* wrow = (const float4*)(Ws + (size_t)m * N);
    float acc = 0.f;
#pragma unroll
    for (int k = 0; k < 4; ++k) {
        float4 a = drow[lane + (k << 6)];
        float4 w = wrow[lane + (k << 6)];
        acc += a.x * w.x + a.y * w.y + a.z * w.z + a.w * w.w;
    }
    acc += __shfl_xor(acc, 1);  acc += __shfl_xor(acc, 2);
    acc += __shfl_xor(acc, 4);  acc += __shfl_xor(acc, 8);
    acc += __shfl_xor(acc, 16); acc += __shfl_xor(acc, 32);
    if (lane == 0) dec_feats[(size_t)b * N + m] = acc + bs[m];
}

// ---------------------------------------------------------------------------
// Kernel 2a: 256x256 8-phase bf16 MFMA GEMM. Inner K-loop/PHASE chip-verified
// (r4-r10: conflicts 0, absmax 0.0039) — UNCHANGED.
// r10 restructure: one block per ROW-TILE, looping ALL FOUR m-tiles and
// accumulating rs[f][reg] += sum_j tanh(.)*v in registers. e becomes a plain
// coalesced store after a cross-wave LDS reduce — NO atomics, NO e-zeroing,
// no 40-VMEM atomic-drain seams.
// m-seam audit: trailing i=7 stages leave all A regions VALID (A m-invariant);
// seam = {vmcnt(0) drain stale B writes (per-wave FIFO orders same-address);
// restage 3 B regions from new m-panel; vmcnt(0); barrier}. Post-seam FIFO
// state (0 outstanding) re-derived against stock PHASE vmcnt(8)s: P0/P2/P4
// consume pre-drained regions; P6 consumes P0/P1 stages confirmed by P5's
// vmcnt(8). Cross-wave LDS writes disjoint (per-wave dc0 chunks).
// ---------------------------------------------------------------------------
#define REGION_A(slot, hk) ((slot)*16384 + (hk)*8192)
#define REGION_B(slot, hk) (32768 + (slot)*16384 + (hk)*8192)

__global__ __launch_bounds__(512, 1)
void score_mfma8_kernel(const short* __restrict__ encb, const short* __restrict__ whb,
                        const float* __restrict__ bh, const float* __restrict__ dec_feats,
                        const float* __restrict__ cov, const float* __restrict__ wc,
                        const float* __restrict__ v, float* __restrict__ e) {
    __shared__ short lds[65536];   // 128 KiB

    // T1: bijective XCD swizzle (512 = 8 * 64). One block per row-tile;
    // whb (2 MB total) L2-resident, A-panel fetched once per block.
    unsigned bid = blockIdx.x;
    unsigned c = (bid & 7u) * 64u + (bid >> 3);
    int rt = (int)c;
    int r0 = rt * 256;

    int t = threadIdx.x, lane = t & 63, w = t >> 6;
    int wm_ = w >> 2, wn_ = w & 3;         // 2 x 4 wave grid
    int cq = lane >> 4, cm = lane & 15;

    int srow = lane >> 2;                              // 0..15 within chunk
    int sg = (lane & 3) ^ ((lane >> 3) & 3);           // logical granule
    const short* aS0 = encb + (size_t)(r0 + w * 16 + srow) * N + sg * 8;
    const short* aS1 = aS0 + (size_t)128 * N;
    const int dc0 = w * 512, dc1 = dc0 + 4096;         // chunk dests (shorts)

    int aoff[8], boff[4];
#pragma unroll
    for (int f = 0; f < 8; ++f) {
        int R = wm_ * 128 + f * 16 + cm;
        aoff[f] = R * 32 + ((cq ^ ((R >> 1) & 3)) << 3);
    }
#pragma unroll
    for (int j = 0; j < 4; ++j) {
        int R = wn_ * 64 + j * 16 + cm;
        boff[j] = R * 32 + ((cq ^ ((R >> 1) & 3)) << 3);
    }

    int bidx = r0 >> 12;
    const float* df = dec_feats + ((size_t)bidx << 10);

    float rs[8][4];
#pragma unroll
    for (int f = 0; f < 8; ++f)
#pragma unroll
        for (int reg = 0; reg < 4; ++reg) rs[f][reg] = 0.f;

#define STAGE(srcp0, srcp1, region, colElem) do {                         \
        int _cc = (colElem) & (N - 1);                                    \
        load_lds16((srcp0) + _cc, &lds[(region) + dc0]);                  \
        load_lds16((srcp1) + _cc, &lds[(region) + dc1]);                  \
    } while (0)

#define PHASE(slot, sub, SRC0, SRC1, SREGION, SCOL) do {                      \
        const int hk_ = (sub) >> 1, mh_ = (sub) & 1;                          \
        if (mh_ == 0) {                                                       \
            _Pragma("unroll")                                                 \
            for (int j = 0; j < 4; ++j)                                       \
                bf[j] = *(const short8*)&lds[REGION_B(slot, hk_) + boff[j]];  \
        }                                                                     \
        short8 af[4];                                                         \
        _Pragma("unroll")                                                     \
        for (int f = 0; f < 4; ++f)                                           \
            af[f] = *(const short8*)&lds[REGION_A(slot, hk_) + aoff[mh_ * 4 + f]]; \
        STAGE(SRC0, SRC1, SREGION, SCOL);                                     \
        __builtin_amdgcn_s_barrier();                                         \
        asm volatile("s_waitcnt lgkmcnt(0)" ::: "memory");                    \
        __builtin_amdgcn_sched_barrier(0);                                    \
        __builtin_amdgcn_s_setprio(1);                                        \
        _Pragma("unroll")                                                     \
        for (int f = 0; f < 4; ++f)                                           \
            _Pragma("unroll")                                                 \
            for (int j = 0; j < 4; ++j)                                       \
                acc[mh_ * 4 + f][j] = __builtin_amdgcn_mfma_f32_16x16x32_bf16(\
                    af[f], bf[j], acc[mh_ * 4 + f][j], 0, 0, 0);              \
        __builtin_amdgcn_s_setprio(0);                                        \
        if (mh_ == 1) asm volatile("s_waitcnt vmcnt(8)" ::: "memory");        \
        __builtin_amdgcn_s_barrier();                                         \
    } while (0)

#pragma unroll 1
    for (int mt = 0; mt < 4; ++mt) {
        int m0 = mt * 256;
        const short* bS0 = whb + (size_t)(m0 + w * 16 + srow) * N + sg * 8;
        const short* bS1 = bS0 + (size_t)128 * N;

        float4v acc[8][4];
#pragma unroll
        for (int f = 0; f < 8; ++f)
#pragma unroll
            for (int j = 0; j < 4; ++j) acc[f][j] = (float4v){0.f, 0.f, 0.f, 0.f};

        if (mt == 0) {
            // Full prologue: 12 loads (A+B, slot0 both halves + slot1 h0).
            STAGE(aS0, aS1, REGION_A(0, 0), 0);
            STAGE(bS0, bS1, REGION_B(0, 0), 0);
            STAGE(aS0, aS1, REGION_A(0, 1), 32);
            STAGE(bS0, bS1, REGION_B(0, 1), 32);
            STAGE(aS0, aS1, REGION_A(1, 0), 64);
            STAGE(bS0, bS1, REGION_B(1, 0), 64);
            asm volatile("s_waitcnt vmcnt(8)" ::: "memory");   // slot0 h0 done
            __builtin_amdgcn_s_barrier();
        } else {
            // m-seam: A regions already valid (restaged to cols 0/32/64 by
            // previous K-loop's trailing stages; A is m-invariant). Drain
            // stale trailing writes, restage the 3 B regions from new panel.
            asm volatile("s_waitcnt vmcnt(0)" ::: "memory");
            STAGE(bS0, bS1, REGION_B(0, 0), 0);
            STAGE(bS0, bS1, REGION_B(0, 1), 32);
            STAGE(bS0, bS1, REGION_B(1, 0), 64);
            asm volatile("s_waitcnt vmcnt(0)" ::: "memory");
            __builtin_amdgcn_s_barrier();
        }

        short8 bf[4];

#pragma unroll 1
        for (int i = 0; i < 8; ++i) {        // 8 iters x 2 K-tiles = K=1024
            int kb = i * 128;
            PHASE(0, 0, aS0, aS1, REGION_A(1, 1), kb + 96);
            PHASE(0, 1, bS0, bS1, REGION_B(1, 1), kb + 96);
            PHASE(0, 2, aS0, aS1, REGION_A(0, 0), kb + 128);
            PHASE(0, 3, bS0, bS1, REGION_B(0, 0), kb + 128);
            PHASE(1, 0, aS0, aS1, REGION_A(0, 1), kb + 160);
            PHASE(1, 1, bS0, bS1, REGION_B(0, 1), kb + 160);
            PHASE(1, 2, aS0, aS1, REGION_A(1, 0), kb + 192);
            PHASE(1, 3, bS0, bS1, REGION_B(1, 0), kb + 192);
        }

        // Accumulate-lite: fold this m-tile into rs (no atomics, no stores).
        // tanh(x) = 1 - 2/(exp2(2*log2e*x)+1). Loads here are drained by the
        // next seam's vmcnt(0) (or are register-consumed before the store).
        float basej[4], wcj[4], vj[4];
#pragma unroll
        for (int j = 0; j < 4; ++j) {
            int m = m0 + wn_ * 64 + j * 16 + cm;
            basej[j] = bh[m] + df[m];
            wcj[j]   = wc[m];
            vj[j]    = v[m];
        }
#pragma unroll
        for (int f = 0; f < 8; ++f) {
            int rbase = r0 + wm_ * 128 + f * 16 + cq * 4;
            float4v cvv = *(const float4v*)&cov[rbase];
            float cv[4] = {cvv.x, cvv.y, cvv.z, cvv.w};
#pragma unroll
            for (int j = 0; j < 4; ++j) {
#pragma unroll
                for (int reg = 0; reg < 4; ++reg) {
                    float val = acc[f][j][reg] + basej[j] + cv[reg] * wcj[j];
                    val = fminf(fmaxf(val, -15.f), 15.f);
                    float t2 = __builtin_amdgcn_exp2f(val * 2.8853900817779268f);
                    float r  = __builtin_amdgcn_rcpf(t2 + 1.f);
                    float th = fmaf(-2.f, r, 1.f);
                    rs[f][reg] = fmaf(th, vj[j], rs[f][reg]);
                }
            }
        }
    }
#undef PHASE
#undef STAGE

    // Final: reduce rs over cm lanes (cols within wave), then cross-wave
    // (4 wn_ groups) via LDS, then ONE coalesced store per row. LDS regions
    // are dead (last K-loop's lgkmcnt(0) preceded its closing barrier).
    asm volatile("s_waitcnt vmcnt(0)" ::: "memory");
    __builtin_amdgcn_s_barrier();
    float* red = (float*)lds;                 // [4 wn_][256 rows]
#pragma unroll
    for (int f = 0; f < 8; ++f) {
#pragma unroll
        for (int reg = 0; reg < 4; ++reg) {
            float p = rs[f][reg];
            p += __shfl_xor(p, 1);
            p += __shfl_xor(p, 2);
            p += __shfl_xor(p, 4);
            p += __shfl_xor(p, 8);
            if (cm == 0)
                red[wn_ * 256 + wm_ * 128 + f * 16 + cq * 4 + reg] = p;
        }
    }
    __syncthreads();
    if (t < 256) {
        float ev = red[t] + red[256 + t] + red[512 + t] + red[768 + t];
        e[r0 + t] = ev;
    }
}

// ---------------------------------------------------------------------------
// Kernel 2b (fallback if workspace too small): fp32-staging MFMA kernel
// (atomic e, needs e pre-zeroed).
// ---------------------------------------------------------------------------
#define BR 128
#define BM 128
#define BK 64
#define LDK (BK + 8)

__global__ __launch_bounds__(256)
void score_mfma_kernel(const float* __restrict__ enc, const float* __restrict__ Wh,
                       const float* __restrict__ bh, const float* __restrict__ dec_feats,
                       const float* __restrict__ cov, const float* __restrict__ wc,
                       const float* __restrict__ v, float* __restrict__ e) {
    __shared__ short As[BR][LDK];
    __shared__ short Bs[BM][LDK];

    unsigned h   = blockIdx.x;
    unsigned xcd = h & 7u;
    unsigned mt  = (h >> 3) & 7u;
    unsigned g   = h >> 6;
    int r0 = (int)(xcd + 8u * g) * BR;
    int m0 = (int)mt * BM;

    int t    = threadIdx.x;
    int lane = t & 63;
    int w    = t >> 6;
    int wr   = (w >> 1) * 64;
    int wm   = (w & 1) * 64;
    int cq   = lane >> 4;
    int cm   = lane & 15;

    float4v acc[4][4];
#pragma unroll
    for (int i = 0; i < 4; ++i)
#pragma unroll
        for (int j = 0; j < 4; ++j) acc[i][j] = (float4v){0.f, 0.f, 0.f, 0.f};

    int srow = t >> 4;
    int scol = (t & 15) * 4;

    for (int k0 = 0; k0 < N; k0 += BK) {
#pragma unroll
        for (int p = 0; p < 8; ++p) {
            int row = p * 16 + srow;
            float4v a = *(const float4v*)(enc + (size_t)(r0 + row) * N + k0 + scol);
            short4v ap = { f2bf(a.x), f2bf(a.y), f2bf(a.z), f2bf(a.w) };
            *(short4v*)&As[row][scol] = ap;
            float4v bq = *(const float4v*)(Wh + (size_t)(m0 + row) * N + k0 + scol);
            short4v bp = { f2bf(bq.x), f2bf(bq.y), f2bf(bq.z), f2bf(bq.w) };
            *(short4v*)&Bs[row][scol] = bp;
        }
        __syncthreads();
#pragma unroll
        for (int ks = 0; ks < BK; ks += 32) {
            short8 af[4], bfr[4];
#pragma unroll
            for (int i = 0; i < 4; ++i)
                af[i] = *(const short8*)&As[wr + i * 16 + cm][ks + cq * 8];
#pragma unroll
            for (int j = 0; j < 4; ++j)
                bfr[j] = *(const short8*)&Bs[wm + j * 16 + cm][ks + cq * 8];
#pragma unroll
            for (int i = 0; i < 4; ++i)
#pragma unroll
                for (int j = 0; j < 4; ++j)
                    acc[i][j] = __builtin_amdgcn_mfma_f32_16x16x32_bf16(
                        af[i], bfr[j], acc[i][j], 0, 0, 0);
        }
        __syncthreads();
    }

    int b = r0 >> 12;
    const float* df = dec_feats + ((size_t)b << 10);

    float basej[4], wcj[4], vj[4];
#pragma unroll
    for (int j = 0; j < 4; ++j) {
        int m = m0 + wm + j * 16 + cm;
        basej[j] = bh[m] + df[m];
        wcj[j]   = wc[m];
        vj[j]    = v[m];
    }

#pragma unroll
    for (int i = 0; i < 4; ++i) {
        int rbase = r0 + wr + i * 16 + cq * 4;
        float cv[4];
#pragma unroll
        for (int reg = 0; reg < 4; ++reg) cv[reg] = cov[rbase + reg];
        float rsl[4] = {0.f, 0.f, 0.f, 0.f};
#pragma unroll
        for (int j = 0; j < 4; ++j) {
#pragma unroll
            for (int reg = 0; reg < 4; ++reg) {
                float val = acc[i][j][reg] + basej[j] + cv[reg] * wcj[j];
                val = fminf(fmaxf(val, -15.f), 15.f);
                float t2 = __builtin_amdgcn_exp2f(val * 2.8853900817779268f);
                float r  = __builtin_amdgcn_rcpf(t2 + 1.f);
                float th = fmaf(-2.f, r, 1.f);
                rsl[reg] = fmaf(th, vj[j], rsl[reg]);
            }
        }
#pragma unroll
        for (int reg = 0; reg < 4; ++reg) {
            float p = rsl[reg];
            p += __shfl_xor(p, 1);
            p += __shfl_xor(p, 2);
            p += __shfl_xor(p, 4);
            p += __shfl_xor(p, 8);
            if (cm == 0) atomicAdd(&e[rbase + reg], p);
        }
    }
}

// ---------------------------------------------------------------------------
// Kernel 3a (fast path): per-chunk masked softmax partials.
// ---------------------------------------------------------------------------
__global__ __launch_bounds__(256)
void softmax_partial_kernel(const float* __restrict__ e, const int* __restrict__ lens,
                            float2* __restrict__ pm) {
    int b = blockIdx.y, ch = blockIdx.x;   // ch 0..7
    int t = threadIdx.x, lane = t & 63, wid = t >> 6;
    int len = lens[b];
    int s0 = ch * 512;
    const float* eb = e + (size_t)b * S + s0;
    float v0 = (s0 + t       < len) ? eb[t]       : -INFINITY;
    float v1 = (s0 + t + 256 < len) ? eb[t + 256] : -INFINITY;
    float mx = fmaxf(v0, v1);
    mx = fmaxf(mx, __shfl_xor(mx, 1));  mx = fmaxf(mx, __shfl_xor(mx, 2));
    mx = fmaxf(mx, __shfl_xor(mx, 4));  mx = fmaxf(mx, __shfl_xor(mx, 8));
    mx = fmaxf(mx, __shfl_xor(mx, 16)); mx = fmaxf(mx, __shfl_xor(mx, 32));
    __shared__ float redm[4], reds[4];
    if (lane == 0) redm[wid] = mx;
    __syncthreads();
    mx = fmaxf(fmaxf(redm[0], redm[1]), fmaxf(redm[2], redm[3]));

    float sum = 0.f;
    if (mx > -INFINITY)   // guard: fully-masked chunk -> (-inf, 0) pair
        sum = exp2f((v0 - mx) * L2E) + exp2f((v1 - mx) * L2E);
    sum += __shfl_xor(sum, 1);  sum += __shfl_xor(sum, 2);
    sum += __shfl_xor(sum, 4);  sum += __shfl_xor(sum, 8);
    sum += __shfl_xor(sum, 16); sum += __shfl_xor(sum, 32);
    if (lane == 0) reds[wid] = sum;
    __syncthreads();
    if (t == 0) {
        float2 p; p.x = mx; p.y = reds[0] + reds[1] + reds[2] + reds[3];
        pm[b * 8 + ch] = p;
    }
}

// ---------------------------------------------------------------------------
// Kernel 4 (fast path): fused softmax-finalize + attn/cov_out + context part.
// ---------------------------------------------------------------------------
#define SCH 64
__global__ __launch_bounds__(256)
void context_part_kernel(const float* __restrict__ e, const int* __restrict__ lens,
                         const float2* __restrict__ pm, const float* __restrict__ cov,
                         const float* __restrict__ enc, float* __restrict__ attn,
                         float* __restrict__ cov_out, float* __restrict__ part) {
    int b  = blockIdx.y;
    int ch = blockIdx.x;
    int s0 = ch * (S / SCH);       // 64 s per block
    int tid = threadIdx.x;
    __shared__ float a_lds[S / SCH];

    if (tid < S / SCH) {
        int len = lens[b];
        const float2* pb = pm + b * 8;
        float M = -INFINITY;
#pragma unroll
        for (int i = 0; i < 8; ++i) M = fmaxf(M, pb[i].x);
        float Ssum = 0.f;
#pragma unroll
        for (int i = 0; i < 8; ++i)
            Ssum += pb[i].y * exp2f((pb[i].x - M) * L2E);
        float inv = 1.f / Ssum;
        int s = s0 + tid;
        float ew = e[(size_t)b * S + s];
        float a = (s < len) ? exp2f((ew - M) * L2E) * inv : 0.f;
        a_lds[tid] = a;
        attn[(size_t)b * S + s] = a;
        cov_out[(size_t)b * S + s] = cov[(size_t)b * S + s] + a;
    }
    __syncthreads();

    const float4* ep = (const float4*)(enc + ((size_t)b * S + s0) * N);
    float4 acc = {0.f, 0.f, 0.f, 0.f};
    for (int s = 0; s < S / SCH; ++s) {
        float a = a_lds[s];
        float4 ev = ep[(size_t)s * (N / 4) + tid];
        acc.x += a * ev.x; acc.y += a * ev.y;
        acc.z += a * ev.z; acc.w += a * ev.w;
    }
    *(float4*)&part[((size_t)b * SCH + ch) * N + tid * 4] = acc;
}

__global__ __launch_bounds__(256)
void context_reduce_kernel(const float* __restrict__ part, float* __restrict__ ctx) {
    int idx = blockIdx.x * 256 + threadIdx.x;   // 0 .. B*N-1
    int b = idx >> 10, n = idx & (N - 1);
    const float* p = part + (size_t)b * SCH * N + n;
    float acc = 0.f;
#pragma unroll
    for (int c2 = 0; c2 < SCH; ++c2) acc += p[(size_t)c2 * N];
    ctx[idx] = acc;
}

// ---------------------------------------------------------------------------
// Fallback helpers: monolithic softmax + atomic context (need ctx pre-zeroed).
// ---------------------------------------------------------------------------
__global__ __launch_bounds__(1024)
void softmax_kernel(const float* __restrict__ e, const int* __restrict__ lens,
                    const float* __restrict__ cov,
                    float* __restrict__ attn, float* __restrict__ cov_out) {
    int b = blockIdx.x, t = threadIdx.x;
    int lane = t & 63, wid = t >> 6;
    int len = lens[b];
    const float* eb = e + (size_t)b * S;
    __shared__ float redm[16], reds[16];

    float ev[4];
    float mx = -INFINITY;
#pragma unroll
    for (int k = 0; k < 4; ++k) {
        int s = t + (k << 10);
        ev[k] = (s < len) ? eb[s] : -INFINITY;
        mx = fmaxf(mx, ev[k]);
    }
    mx = fmaxf(mx, __shfl_xor(mx, 1));  mx = fmaxf(mx, __shfl_xor(mx, 2));
    mx = fmaxf(mx, __shfl_xor(mx, 4));  mx = fmaxf(mx, __shfl_xor(mx, 8));
    mx = fmaxf(mx, __shfl_xor(mx, 16)); mx = fmaxf(mx, __shfl_xor(mx, 32));
    if (lane == 0) redm[wid] = mx;
    __syncthreads();
    if (t < 16) {
        float v2 = redm[t];
        v2 = fmaxf(v2, __shfl_xor(v2, 1)); v2 = fmaxf(v2, __shfl_xor(v2, 2));
        v2 = fmaxf(v2, __shfl_xor(v2, 4)); v2 = fmaxf(v2, __shfl_xor(v2, 8));
        if (t == 0) redm[0] = v2;
    }
    __syncthreads();
    mx = redm[0];

    float ex[4];
    float sum = 0.f;
#pragma unroll
    for (int k = 0; k < 4; ++k) {
        ex[k] = exp2f((ev[k] - mx) * L2E);
        sum += ex[k];
    }
    sum += __shfl_xor(sum, 1);  sum += __shfl_xor(sum, 2);
    sum += __shfl_xor(sum, 4);  sum += __shfl_xor(sum, 8);
    sum += __shfl_xor(sum, 16); sum += __shfl_xor(sum, 32);
    if (lane == 0) reds[wid] = sum;
    __syncthreads();
    if (t < 16) {
        float v2 = reds[t];
        v2 += __shfl_xor(v2, 1); v2 += __shfl_xor(v2, 2);
        v2 += __shfl_xor(v2, 4); v2 += __shfl_xor(v2, 8);
        if (t == 0) reds[0] = v2;
    }
    __syncthreads();
    float inv = 1.f / reds[0];

#pragma unroll
    for (int k = 0; k < 4; ++k) {
        int s = t + (k << 10);
        float a = ex[k] * inv;
        attn[(size_t)b * S + s] = a;
        cov_out[(size_t)b * S + s] = cov[(size_t)b * S + s] + a;
    }
}

__global__ __launch_bounds__(256)
void context_kernel(const float* __restrict__ attn, const float* __restrict__ enc,
                    float* __restrict__ ctx) {
    int b  = blockIdx.y;
    int s0 = blockIdx.x * (S / SCH);
    int n4 = threadIdx.x;
    const float4* ep = (const float4*)(enc + ((size_t)b * S + s0) * N);
    float4 acc = {0.f, 0.f, 0.f, 0.f};
    for (int s = 0; s < S / SCH; ++s) {
        float a = attn[(size_t)b * S + s0 + s];
        float4 ev = ep[(size_t)s * (N / 4) + n4];
        acc.x += a * ev.x; acc.y += a * ev.y;
        acc.z += a * ev.z; acc.w += a * ev.w;
    }
    float* cp = ctx + (size_t)b * N + n4 * 4;
    atomicAdd(cp + 0, acc.x);
    atomicAdd(cp + 1, acc.y);
    atomicAdd(cp + 2, acc.z);
    atomicAdd(cp + 3, acc.w);
}

// ---------------------------------------------------------------------------
extern "C" void kernel_launch(void* const* d_in, const int* in_sizes, int n_in,
                              void* d_out, int out_size, void* d_ws, size_t ws_size,
                              hipStream_t stream) {
    const float* dec  = (const float*)d_in[0];
    const float* enc  = (const float*)d_in[1];
    const int*   lens = (const int*)  d_in[2];
    const float* cov  = (const float*)d_in[3];
    const float* Wh   = (const float*)d_in[4];
    const float* bh   = (const float*)d_in[5];
    const float* Ws   = (const float*)d_in[6];
    const float* bs   = (const float*)d_in[7];
    const float* wc   = (const float*)d_in[8];
    const float* v    = (const float*)d_in[9];

    float* out     = (float*)d_out;
    float* ctx     = out;                    // B*N
    float* attn    = out + (size_t)B * N;    // B*S
    float* cov_out = attn + (size_t)B * S;   // B*S

    size_t off_e    = (size_t)B * N * 4;
    size_t off_encb = off_e + (size_t)B * S * 4;
    size_t off_whb  = off_encb + (size_t)B * S * N * 2;
    size_t off_part = off_whb + (size_t)N * N * 2;
    size_t off_pm   = off_part + (size_t)B * SCH * N * 4;
    size_t need     = off_pm + (size_t)B * 8 * sizeof(float2);

    float* dec_feats = (float*)d_ws;
    float* e         = (float*)((char*)d_ws + off_e);

    if (ws_size >= need) {
        short*  encb = (short*)((char*)d_ws + off_encb);
        short*  whb  = (short*)((char*)d_ws + off_whb);
        float*  part = (float*)((char*)d_ws + off_part);
        float2* pm   = (float2*)((char*)d_ws + off_pm);
        prep_cvt_kernel<<<10256, 256, 0, stream>>>(dec, Ws, bs, enc, Wh,
                                                   dec_feats, encb, whb);
        score_mfma8_kernel<<<512, 512, 0, stream>>>(
            encb, whb, bh, dec_feats, cov, wc, v, e);
        softmax_partial_kernel<<<dim3(8, B), 256, 0, stream>>>(e, lens, pm);
        context_part_kernel<<<dim3(SCH, B), 256, 0, stream>>>(
            e, lens, pm, cov, enc, attn, cov_out, part);
        context_reduce_kernel<<<(B * N) / 256, 256, 0, stream>>>(part, ctx);
    } else {
        prep_kernel<<<8192, 256, 0, stream>>>(dec, Ws, bs, dec_feats, e);
        hipMemsetAsync(ctx, 0, (size_t)B * N * sizeof(float), stream);
        score_mfma_kernel<<<(B * S / BR) * (N / BM), 256, 0, stream>>>(
            enc, Wh, bh, dec_feats, cov, wc, v, e);
        softmax_kernel<<<B, 1024, 0, stream>>>(e, lens, cov, attn, cov_out);
        context_kernel<<<dim3(SCH, B), 256, 0, stream>>>(attn, enc, ctx);
    }
}

// Round 13
// 1063.044 us; speedup vs baseline: 1.0956x; 1.0572x over previous
//
#include <hip/hip_runtime.h>
#include <math.h>

#define B 32
#define S 4096
#define N 1024
#define L2E 1.4426950408889634f

typedef short short8 __attribute__((ext_vector_type(8)));
typedef short short4v __attribute__((ext_vector_type(4)));
typedef float float4v __attribute__((ext_vector_type(4)));

__device__ inline short f2bf(float f) {
    unsigned u = __builtin_bit_cast(unsigned, f);
    u += 0x7fffu + ((u >> 16) & 1u);   // RNE
    return (short)(u >> 16);
}

__device__ inline float bf2f(short s) {
    unsigned u = ((unsigned)(unsigned short)s) << 16;
    return __builtin_bit_cast(float, u);
}

// async global->LDS DMA, 16 B per lane. LDS dest wave-uniform + lane*16 linear.
__device__ __forceinline__ void load_lds16(const void* g, void* l) {
    __builtin_amdgcn_global_load_lds(
        (const __attribute__((address_space(1))) void*)g,
        (__attribute__((address_space(3))) void*)l, 16, 0, 0);
}

// ---------------------------------------------------------------------------
// Kernel 1 (fast path): fused front-end.
//   blocks [0,2048):    cvt enc fp32->bf16.
//   blocks [2048,2064):  cvt Wh fp32->bf16.
//   blocks [2064,10256): dec_feats, one wave per (b,m), coalesced + shuffle.
// ---------------------------------------------------------------------------
__global__ __launch_bounds__(256)
void prep_cvt_kernel(const float* __restrict__ dec, const float* __restrict__ Ws,
                     const float* __restrict__ bs, const float* __restrict__ enc,
                     const float* __restrict__ Wh, float* __restrict__ dec_feats,
                     short* __restrict__ encb, short* __restrict__ whb) {
    unsigned bid = blockIdx.x;
    int tid = threadIdx.x;
    if (bid < 2048u) {
        const size_t n8e = (size_t)B * S * N / 8;
        for (size_t i = (size_t)bid * 256 + tid; i < n8e; i += 2048u * 256u) {
            const float4v* s = (const float4v*)(enc + i * 8);
            float4v a = s[0], b = s[1];
            short8 o = { f2bf(a.x), f2bf(a.y), f2bf(a.z), f2bf(a.w),
                         f2bf(b.x), f2bf(b.y), f2bf(b.z), f2bf(b.w) };
            *(short8*)(encb + i * 8) = o;
        }
    } else if (bid < 2064u) {
        const size_t n8w = (size_t)N * N / 8;
        for (size_t i = (size_t)(bid - 2048u) * 256 + tid; i < n8w; i += 16u * 256u) {
            const float4v* s = (const float4v*)(Wh + i * 8);
            float4v a = s[0], b = s[1];
            short8 o = { f2bf(a.x), f2bf(a.y), f2bf(a.z), f2bf(a.w),
                         f2bf(b.x), f2bf(b.y), f2bf(b.z), f2bf(b.w) };
            *(short8*)(whb + i * 8) = o;
        }
    } else {
        int wid  = (int)(bid - 2064u) * 4 + (tid >> 6);  // 0..32767 = (m,b)
        int lane = tid & 63;
        int m = wid >> 5, b = wid & 31;
        const float4* drow = (const float4*)(dec + (size_t)b * N);
        const float4* wrow = (const float4*)(Ws + (size_t)m * N);
        float acc = 0.f;
#pragma unroll
        for (int k = 0; k < 4; ++k) {
            float4 a = drow[lane + (k << 6)];
            float4 w = wrow[lane + (k << 6)];
            acc += a.x * w.x + a.y * w.y + a.z * w.z + a.w * w.w;
        }
        acc += __shfl_xor(acc, 1);  acc += __shfl_xor(acc, 2);
        acc += __shfl_xor(acc, 4);  acc += __shfl_xor(acc, 8);
        acc += __shfl_xor(acc, 16); acc += __shfl_xor(acc, 32);
        if (lane == 0) dec_feats[(size_t)b * N + m] = acc + bs[m];
    }
}

// ---------------------------------------------------------------------------
// Kernel 1b (fallback path): zero(e) + dec_feats only.
// ---------------------------------------------------------------------------
__global__ __launch_bounds__(256)
void prep_kernel(const float* __restrict__ dec, const float* __restrict__ Ws,
                 const float* __restrict__ bs, float* __restrict__ dec_feats,
                 float* __restrict__ e) {
    int tg = blockIdx.x * 256 + threadIdx.x;
    if (tg < B * S) e[tg] = 0.f;
    int wid  = (blockIdx.x << 2) + (threadIdx.x >> 6);
    int lane = threadIdx.x & 63;
    int m = wid >> 5, b = wid & 31;
    const float4* drow = (const float4*)(dec + (size_t)b * N);
    const float4* wrow = (const float4*)(Ws + (size_t)m * N);
    float acc = 0.f;
#pragma unroll
    for (int k = 0; k < 4; ++k) {
        float4 a = drow[lane + (k << 6)];
        float4 w = wrow[lane + (k << 6)];
        acc += a.x * w.x + a.y * w.y + a.z * w.z + a.w * w.w;
    }
    acc += __shfl_xor(acc, 1);  acc += __shfl_xor(acc, 2);
    acc += __shfl_xor(acc, 4);  acc += __shfl_xor(acc, 8);
    acc += __shfl_xor(acc, 16); acc += __shfl_xor(acc, 32);
    if (lane == 0) dec_feats[(size_t)b * N + m] = acc + bs[m];
}

// ---------------------------------------------------------------------------
// Kernel 2a: 256x256 8-phase bf16 MFMA GEMM. Inner K-loop/PHASE + m-seam
// chip-verified (r4-r11: conflicts 0, absmax 0.0039, no-atomic form r11) —
// UNCHANGED. r11 addition: epilogue also emits this chunk's masked softmax
// partial (max, sum_exp) -> pm[b*16+chunk], removing the softmax_partial
// kernel. Uses dead LDS (+4KB past the e-reduce region) + 2 extra barriers.
// ---------------------------------------------------------------------------
#define REGION_A(slot, hk) ((slot)*16384 + (hk)*8192)
#define REGION_B(slot, hk) (32768 + (slot)*16384 + (hk)*8192)

__global__ __launch_bounds__(512, 1)
void score_mfma8_kernel(const short* __restrict__ encb, const short* __restrict__ whb,
                        const float* __restrict__ bh, const float* __restrict__ dec_feats,
                        const float* __restrict__ cov, const float* __restrict__ wc,
                        const float* __restrict__ v, const int* __restrict__ lens,
                        float* __restrict__ e, float2* __restrict__ pm) {
    __shared__ short lds[65536];   // 128 KiB

    // T1: bijective XCD swizzle (512 = 8 * 64). One block per row-tile;
    // whb (2 MB total) L2-resident, A-panel fetched once per block.
    unsigned bid = blockIdx.x;
    unsigned c = (bid & 7u) * 64u + (bid >> 3);
    int rt = (int)c;
    int r0 = rt * 256;

    int t = threadIdx.x, lane = t & 63, w = t >> 6;
    int wm_ = w >> 2, wn_ = w & 3;         // 2 x 4 wave grid
    int cq = lane >> 4, cm = lane & 15;

    int srow = lane >> 2;                              // 0..15 within chunk
    int sg = (lane & 3) ^ ((lane >> 3) & 3);           // logical granule
    const short* aS0 = encb + (size_t)(r0 + w * 16 + srow) * N + sg * 8;
    const short* aS1 = aS0 + (size_t)128 * N;
    const int dc0 = w * 512, dc1 = dc0 + 4096;         // chunk dests (shorts)

    int aoff[8], boff[4];
#pragma unroll
    for (int f = 0; f < 8; ++f) {
        int R = wm_ * 128 + f * 16 + cm;
        aoff[f] = R * 32 + ((cq ^ ((R >> 1) & 3)) << 3);
    }
#pragma unroll
    for (int j = 0; j < 4; ++j) {
        int R = wn_ * 64 + j * 16 + cm;
        boff[j] = R * 32 + ((cq ^ ((R >> 1) & 3)) << 3);
    }

    int bidx = r0 >> 12;
    const float* df = dec_feats + ((size_t)bidx << 10);

    float rs[8][4];
#pragma unroll
    for (int f = 0; f < 8; ++f)
#pragma unroll
        for (int reg = 0; reg < 4; ++reg) rs[f][reg] = 0.f;

#define STAGE(srcp0, srcp1, region, colElem) do {                         \
        int _cc = (colElem) & (N - 1);                                    \
        load_lds16((srcp0) + _cc, &lds[(region) + dc0]);                  \
        load_lds16((srcp1) + _cc, &lds[(region) + dc1]);                  \
    } while (0)

#define PHASE(slot, sub, SRC0, SRC1, SREGION, SCOL) do {                      \
        const int hk_ = (sub) >> 1, mh_ = (sub) & 1;                          \
        if (mh_ == 0) {                                                       \
            _Pragma("unroll")                                                 \
            for (int j = 0; j < 4; ++j)                                       \
                bf[j] = *(const short8*)&lds[REGION_B(slot, hk_) + boff[j]];  \
        }                                                                     \
        short8 af[4];                                                         \
        _Pragma("unroll")                                                     \
        for (int f = 0; f < 4; ++f)                                           \
            af[f] = *(const short8*)&lds[REGION_A(slot, hk_) + aoff[mh_ * 4 + f]]; \
        STAGE(SRC0, SRC1, SREGION, SCOL);                                     \
        __builtin_amdgcn_s_barrier();                                         \
        asm volatile("s_waitcnt lgkmcnt(0)" ::: "memory");                    \
        __builtin_amdgcn_sched_barrier(0);                                    \
        __builtin_amdgcn_s_setprio(1);                                        \
        _Pragma("unroll")                                                     \
        for (int f = 0; f < 4; ++f)                                           \
            _Pragma("unroll")                                                 \
            for (int j = 0; j < 4; ++j)                                       \
                acc[mh_ * 4 + f][j] = __builtin_amdgcn_mfma_f32_16x16x32_bf16(\
                    af[f], bf[j], acc[mh_ * 4 + f][j], 0, 0, 0);              \
        __builtin_amdgcn_s_setprio(0);                                        \
        if (mh_ == 1) asm volatile("s_waitcnt vmcnt(8)" ::: "memory");        \
        __builtin_amdgcn_s_barrier();                                         \
    } while (0)

#pragma unroll 1
    for (int mt = 0; mt < 4; ++mt) {
        int m0 = mt * 256;
        const short* bS0 = whb + (size_t)(m0 + w * 16 + srow) * N + sg * 8;
        const short* bS1 = bS0 + (size_t)128 * N;

        float4v acc[8][4];
#pragma unroll
        for (int f = 0; f < 8; ++f)
#pragma unroll
            for (int j = 0; j < 4; ++j) acc[f][j] = (float4v){0.f, 0.f, 0.f, 0.f};

        if (mt == 0) {
            // Full prologue: 12 loads (A+B, slot0 both halves + slot1 h0).
            STAGE(aS0, aS1, REGION_A(0, 0), 0);
            STAGE(bS0, bS1, REGION_B(0, 0), 0);
            STAGE(aS0, aS1, REGION_A(0, 1), 32);
            STAGE(bS0, bS1, REGION_B(0, 1), 32);
            STAGE(aS0, aS1, REGION_A(1, 0), 64);
            STAGE(bS0, bS1, REGION_B(1, 0), 64);
            asm volatile("s_waitcnt vmcnt(8)" ::: "memory");   // slot0 h0 done
            __builtin_amdgcn_s_barrier();
        } else {
            // m-seam (audited r10): A regions valid (m-invariant, restaged by
            // trailing stages); drain stale B writes, restage 3 B regions.
            asm volatile("s_waitcnt vmcnt(0)" ::: "memory");
            STAGE(bS0, bS1, REGION_B(0, 0), 0);
            STAGE(bS0, bS1, REGION_B(0, 1), 32);
            STAGE(bS0, bS1, REGION_B(1, 0), 64);
            asm volatile("s_waitcnt vmcnt(0)" ::: "memory");
            __builtin_amdgcn_s_barrier();
        }

        short8 bf[4];

#pragma unroll 1
        for (int i = 0; i < 8; ++i) {        // 8 iters x 2 K-tiles = K=1024
            int kb = i * 128;
            PHASE(0, 0, aS0, aS1, REGION_A(1, 1), kb + 96);
            PHASE(0, 1, bS0, bS1, REGION_B(1, 1), kb + 96);
            PHASE(0, 2, aS0, aS1, REGION_A(0, 0), kb + 128);
            PHASE(0, 3, bS0, bS1, REGION_B(0, 0), kb + 128);
            PHASE(1, 0, aS0, aS1, REGION_A(0, 1), kb + 160);
            PHASE(1, 1, bS0, bS1, REGION_B(0, 1), kb + 160);
            PHASE(1, 2, aS0, aS1, REGION_A(1, 0), kb + 192);
            PHASE(1, 3, bS0, bS1, REGION_B(1, 0), kb + 192);
        }

        // Accumulate-lite: fold this m-tile into rs (no atomics, no stores).
        float basej[4], wcj[4], vj[4];
#pragma unroll
        for (int j = 0; j < 4; ++j) {
            int m = m0 + wn_ * 64 + j * 16 + cm;
            basej[j] = bh[m] + df[m];
            wcj[j]   = wc[m];
            vj[j]    = v[m];
        }
#pragma unroll
        for (int f = 0; f < 8; ++f) {
            int rbase = r0 + wm_ * 128 + f * 16 + cq * 4;
            float4v cvv = *(const float4v*)&cov[rbase];
            float cv[4] = {cvv.x, cvv.y, cvv.z, cvv.w};
#pragma unroll
            for (int j = 0; j < 4; ++j) {
#pragma unroll
                for (int reg = 0; reg < 4; ++reg) {
                    float val = acc[f][j][reg] + basej[j] + cv[reg] * wcj[j];
                    val = fminf(fmaxf(val, -15.f), 15.f);
                    float t2 = __builtin_amdgcn_exp2f(val * 2.8853900817779268f);
                    float r  = __builtin_amdgcn_rcpf(t2 + 1.f);
                    float th = fmaf(-2.f, r, 1.f);
                    rs[f][reg] = fmaf(th, vj[j], rs[f][reg]);
                }
            }
        }
    }
#undef PHASE
#undef STAGE

    // Final: reduce rs over cm lanes, cross-wave via LDS, ONE coalesced
    // e store per row, then the masked softmax partial for this 256-chunk.
    asm volatile("s_waitcnt vmcnt(0)" ::: "memory");
    __builtin_amdgcn_s_barrier();
    float* red  = (float*)lds;                 // [4 wn_][256 rows]
    float* red2 = red + 1024;                  // pm reduce scratch (16 floats)
#pragma unroll
    for (int f = 0; f < 8; ++f) {
#pragma unroll
        for (int reg = 0; reg < 4; ++reg) {
            float p = rs[f][reg];
            p += __shfl_xor(p, 1);
            p += __shfl_xor(p, 2);
            p += __shfl_xor(p, 4);
            p += __shfl_xor(p, 8);
            if (cm == 0)
                red[wn_ * 256 + wm_ * 128 + f * 16 + cq * 4 + reg] = p;
        }
    }
    __syncthreads();
    int len = lens[bidx];
    float mval = -INFINITY;
    if (t < 256) {
        float ev = red[t] + red[256 + t] + red[512 + t] + red[768 + t];
        e[r0 + t] = ev;
        int s = (r0 & (S - 1)) + t;
        mval = (s < len) ? ev : -INFINITY;
    }
    // all 8 waves participate (waves 4-7 carry -inf / 0)
    float mx = mval;
    mx = fmaxf(mx, __shfl_xor(mx, 1));  mx = fmaxf(mx, __shfl_xor(mx, 2));
    mx = fmaxf(mx, __shfl_xor(mx, 4));  mx = fmaxf(mx, __shfl_xor(mx, 8));
    mx = fmaxf(mx, __shfl_xor(mx, 16)); mx = fmaxf(mx, __shfl_xor(mx, 32));
    if (lane == 0) red2[w] = mx;
    __syncthreads();
    float M = -INFINITY;
#pragma unroll
    for (int i = 0; i < 8; ++i) M = fmaxf(M, red2[i]);
    float sm = (M > -INFINITY) ? exp2f((mval - M) * L2E) : 0.f;  // -inf -> 0
    sm += __shfl_xor(sm, 1);  sm += __shfl_xor(sm, 2);
    sm += __shfl_xor(sm, 4);  sm += __shfl_xor(sm, 8);
    sm += __shfl_xor(sm, 16); sm += __shfl_xor(sm, 32);
    if (lane == 0) red2[8 + w] = sm;
    __syncthreads();
    if (t == 0) {
        float tot = red2[8] + red2[9] + red2[10] + red2[11] +
                    red2[12] + red2[13] + red2[14] + red2[15];
        float2 p; p.x = M; p.y = tot;
        pm[(bidx << 4) + ((r0 >> 8) & 15)] = p;
    }
}

// ---------------------------------------------------------------------------
// Kernel 2b (fallback if workspace too small): fp32-staging MFMA kernel
// (atomic e, needs e pre-zeroed).
// ---------------------------------------------------------------------------
#define BR 128
#define BM 128
#define BK 64
#define LDK (BK + 8)

__global__ __launch_bounds__(256)
void score_mfma_kernel(const float* __restrict__ enc, const float* __restrict__ Wh,
                       const float* __restrict__ bh, const float* __restrict__ dec_feats,
                       const float* __restrict__ cov, const float* __restrict__ wc,
                       const float* __restrict__ v, float* __restrict__ e) {
    __shared__ short As[BR][LDK];
    __shared__ short Bs[BM][LDK];

    unsigned h   = blockIdx.x;
    unsigned xcd = h & 7u;
    unsigned mt  = (h >> 3) & 7u;
    unsigned g   = h >> 6;
    int r0 = (int)(xcd + 8u * g) * BR;
    int m0 = (int)mt * BM;

    int t    = threadIdx.x;
    int lane = t & 63;
    int w    = t >> 6;
    int wr   = (w >> 1) * 64;
    int wm   = (w & 1) * 64;
    int cq   = lane >> 4;
    int cm   = lane & 15;

    float4v acc[4][4];
#pragma unroll
    for (int i = 0; i < 4; ++i)
#pragma unroll
        for (int j = 0; j < 4; ++j) acc[i][j] = (float4v){0.f, 0.f, 0.f, 0.f};

    int srow = t >> 4;
    int scol = (t & 15) * 4;

    for (int k0 = 0; k0 < N; k0 += BK) {
#pragma unroll
        for (int p = 0; p < 8; ++p) {
            int row = p * 16 + srow;
            float4v a = *(const float4v*)(enc + (size_t)(r0 + row) * N + k0 + scol);
            short4v ap = { f2bf(a.x), f2bf(a.y), f2bf(a.z), f2bf(a.w) };
            *(short4v*)&As[row][scol] = ap;
            float4v bq = *(const float4v*)(Wh + (size_t)(m0 + row) * N + k0 + scol);
            short4v bp = { f2bf(bq.x), f2bf(bq.y), f2bf(bq.z), f2bf(bq.w) };
            *(short4v*)&Bs[row][scol] = bp;
        }
        __syncthreads();
#pragma unroll
        for (int ks = 0; ks < BK; ks += 32) {
            short8 af[4], bfr[4];
#pragma unroll
            for (int i = 0; i < 4; ++i)
                af[i] = *(const short8*)&As[wr + i * 16 + cm][ks + cq * 8];
#pragma unroll
            for (int j = 0; j < 4; ++j)
                bfr[j] = *(const short8*)&Bs[wm + j * 16 + cm][ks + cq * 8];
#pragma unroll
            for (int i = 0; i < 4; ++i)
#pragma unroll
                for (int j = 0; j < 4; ++j)
                    acc[i][j] = __builtin_amdgcn_mfma_f32_16x16x32_bf16(
                        af[i], bfr[j], acc[i][j], 0, 0, 0);
        }
        __syncthreads();
    }

    int b = r0 >> 12;
    const float* df = dec_feats + ((size_t)b << 10);

    float basej[4], wcj[4], vj[4];
#pragma unroll
    for (int j = 0; j < 4; ++j) {
        int m = m0 + wm + j * 16 + cm;
        basej[j] = bh[m] + df[m];
        wcj[j]   = wc[m];
        vj[j]    = v[m];
    }

#pragma unroll
    for (int i = 0; i < 4; ++i) {
        int rbase = r0 + wr + i * 16 + cq * 4;
        float cv[4];
#pragma unroll
        for (int reg = 0; reg < 4; ++reg) cv[reg] = cov[rbase + reg];
        float rsl[4] = {0.f, 0.f, 0.f, 0.f};
#pragma unroll
        for (int j = 0; j < 4; ++j) {
#pragma unroll
            for (int reg = 0; reg < 4; ++reg) {
                float val = acc[i][j][reg] + basej[j] + cv[reg] * wcj[j];
                val = fminf(fmaxf(val, -15.f), 15.f);
                float t2 = __builtin_amdgcn_exp2f(val * 2.8853900817779268f);
                float r  = __builtin_amdgcn_rcpf(t2 + 1.f);
                float th = fmaf(-2.f, r, 1.f);
                rsl[reg] = fmaf(th, vj[j], rsl[reg]);
            }
        }
#pragma unroll
        for (int reg = 0; reg < 4; ++reg) {
            float p = rsl[reg];
            p += __shfl_xor(p, 1);
            p += __shfl_xor(p, 2);
            p += __shfl_xor(p, 4);
            p += __shfl_xor(p, 8);
            if (cm == 0) atomicAdd(&e[rbase + reg], p);
        }
    }
}

// ---------------------------------------------------------------------------
// Kernel 4 (fast path): fused softmax-finalize + attn/cov_out + context part.
// Merges the 16 per-chunk (max,sum) pairs (logsumexp merge == monolithic
// softmax algebraically). Context reads bf16 encb (halved traffic; error
// ~1e-4 absolute, two orders under the 0.0039 absmax set by the bf16 GEMM).
// ---------------------------------------------------------------------------
#define SCH 64
__global__ __launch_bounds__(256)
void context_part_kernel(const float* __restrict__ e, const int* __restrict__ lens,
                         const float2* __restrict__ pm, const float* __restrict__ cov,
                         const short* __restrict__ encb, float* __restrict__ attn,
                         float* __restrict__ cov_out, float* __restrict__ part) {
    int b  = blockIdx.y;
    int ch = blockIdx.x;
    int s0 = ch * (S / SCH);       // 64 s per block
    int tid = threadIdx.x;
    __shared__ float a_lds[S / SCH];

    if (tid < S / SCH) {
        int len = lens[b];
        const float2* pb = pm + b * 16;
        float M = -INFINITY;
#pragma unroll
        for (int i = 0; i < 16; ++i) M = fmaxf(M, pb[i].x);
        float Ssum = 0.f;
#pragma unroll
        for (int i = 0; i < 16; ++i)   // (-inf,0) pairs contribute 0
            Ssum += pb[i].y * exp2f((pb[i].x - M) * L2E);
        float inv = 1.f / Ssum;
        int s = s0 + tid;
        float ew = e[(size_t)b * S + s];
        float a = (s < len) ? exp2f((ew - M) * L2E) * inv : 0.f;
        a_lds[tid] = a;
        attn[(size_t)b * S + s] = a;
        cov_out[(size_t)b * S + s] = cov[(size_t)b * S + s] + a;
    }
    __syncthreads();

    const short* ep = encb + ((size_t)b * S + s0) * N + tid * 4;
    float acc0 = 0.f, acc1 = 0.f, acc2 = 0.f, acc3 = 0.f;
    for (int s = 0; s < S / SCH; ++s) {
        float a = a_lds[s];
        short4v ev = *(const short4v*)(ep + (size_t)s * N);
        acc0 = fmaf(a, bf2f(ev[0]), acc0);
        acc1 = fmaf(a, bf2f(ev[1]), acc1);
        acc2 = fmaf(a, bf2f(ev[2]), acc2);
        acc3 = fmaf(a, bf2f(ev[3]), acc3);
    }
    float4v o = {acc0, acc1, acc2, acc3};
    *(float4v*)&part[((size_t)b * SCH + ch) * N + tid * 4] = o;
}

__global__ __launch_bounds__(256)
void context_reduce_kernel(const float* __restrict__ part, float* __restrict__ ctx) {
    int idx = blockIdx.x * 256 + threadIdx.x;   // 0 .. B*N-1
    int b = idx >> 10, n = idx & (N - 1);
    const float* p = part + (size_t)b * SCH * N + n;
    float acc = 0.f;
#pragma unroll
    for (int c2 = 0; c2 < SCH; ++c2) acc += p[(size_t)c2 * N];
    ctx[idx] = acc;
}

// ---------------------------------------------------------------------------
// Fallback helpers: monolithic softmax + atomic context (need ctx pre-zeroed).
// ---------------------------------------------------------------------------
__global__ __launch_bounds__(1024)
void softmax_kernel(const float* __restrict__ e, const int* __restrict__ lens,
                    const float* __restrict__ cov,
                    float* __restrict__ attn, float* __restrict__ cov_out) {
    int b = blockIdx.x, t = threadIdx.x;
    int lane = t & 63, wid = t >> 6;
    int len = lens[b];
    const float* eb = e + (size_t)b * S;
    __shared__ float redm[16], reds[16];

    float ev[4];
    float mx = -INFINITY;
#pragma unroll
    for (int k = 0; k < 4; ++k) {
        int s = t + (k << 10);
        ev[k] = (s < len) ? eb[s] : -INFINITY;
        mx = fmaxf(mx, ev[k]);
    }
    mx = fmaxf(mx, __shfl_xor(mx, 1));  mx = fmaxf(mx, __shfl_xor(mx, 2));
    mx = fmaxf(mx, __shfl_xor(mx, 4));  mx = fmaxf(mx, __shfl_xor(mx, 8));
    mx = fmaxf(mx, __shfl_xor(mx, 16)); mx = fmaxf(mx, __shfl_xor(mx, 32));
    if (lane == 0) redm[wid] = mx;
    __syncthreads();
    if (t < 16) {
        float v2 = redm[t];
        v2 = fmaxf(v2, __shfl_xor(v2, 1)); v2 = fmaxf(v2, __shfl_xor(v2, 2));
        v2 = fmaxf(v2, __shfl_xor(v2, 4)); v2 = fmaxf(v2, __shfl_xor(v2, 8));
        if (t == 0) redm[0] = v2;
    }
    __syncthreads();
    mx = redm[0];

    float ex[4];
    float sum = 0.f;
#pragma unroll
    for (int k = 0; k < 4; ++k) {
        ex[k] = exp2f((ev[k] - mx) * L2E);
        sum += ex[k];
    }
    sum += __shfl_xor(sum, 1);  sum += __shfl_xor(sum, 2);
    sum += __shfl_xor(sum, 4);  sum += __shfl_xor(sum, 8);
    sum += __shfl_xor(sum, 16); sum += __shfl_xor(sum, 32);
    if (lane == 0) reds[wid] = sum;
    __syncthreads();
    if (t < 16) {
        float v2 = reds[t];
        v2 += __shfl_xor(v2, 1); v2 += __shfl_xor(v2, 2);
        v2 += __shfl_xor(v2, 4); v2 += __shfl_xor(v2, 8);
        if (t == 0) reds[0] = v2;
    }
    __syncthreads();
    float inv = 1.f / reds[0];

#pragma unroll
    for (int k = 0; k < 4; ++k) {
        int s = t + (k << 10);
        float a = ex[k] * inv;
        attn[(size_t)b * S + s] = a;
        cov_out[(size_t)b * S + s] = cov[(size_t)b * S + s] + a;
    }
}

__global__ __launch_bounds__(256)
void context_kernel(const float* __restrict__ attn, const float* __restrict__ enc,
                    float* __restrict__ ctx) {
    int b  = blockIdx.y;
    int s0 = blockIdx.x * (S / SCH);
    int n4 = threadIdx.x;
    const float4* ep = (const float4*)(enc + ((size_t)b * S + s0) * N);
    float4 acc = {0.f, 0.f, 0.f, 0.f};
    for (int s = 0; s < S / SCH; ++s) {
        float a = attn[(size_t)b * S + s0 + s];
        float4 ev = ep[(size_t)s * (N / 4) + n4];
        acc.x += a * ev.x; acc.y += a * ev.y;
        acc.z += a * ev.z; acc.w += a * ev.w;
    }
    float* cp = ctx + (size_t)b * N + n4 * 4;
    atomicAdd(cp + 0, acc.x);
    atomicAdd(cp + 1, acc.y);
    atomicAdd(cp + 2, acc.z);
    atomicAdd(cp + 3, acc.w);
}

// ---------------------------------------------------------------------------
extern "C" void kernel_launch(void* const* d_in, const int* in_sizes, int n_in,
                              void* d_out, int out_size, void* d_ws, size_t ws_size,
                              hipStream_t stream) {
    const float* dec  = (const float*)d_in[0];
    const float* enc  = (const float*)d_in[1];
    const int*   lens = (const int*)  d_in[2];
    const float* cov  = (const float*)d_in[3];
    const float* Wh   = (const float*)d_in[4];
    const float* bh   = (const float*)d_in[5];
    const float* Ws   = (const float*)d_in[6];
    const float* bs   = (const float*)d_in[7];
    const float* wc   = (const float*)d_in[8];
    const float* v    = (const float*)d_in[9];

    float* out     = (float*)d_out;
    float* ctx     = out;                    // B*N
    float* attn    = out + (size_t)B * N;    // B*S
    float* cov_out = attn + (size_t)B * S;   // B*S

    size_t off_e    = (size_t)B * N * 4;
    size_t off_encb = off_e + (size_t)B * S * 4;
    size_t off_whb  = off_encb + (size_t)B * S * N * 2;
    size_t off_part = off_whb + (size_t)N * N * 2;
    size_t off_pm   = off_part + (size_t)B * SCH * N * 4;
    size_t need     = off_pm + (size_t)B * 16 * sizeof(float2);

    float* dec_feats = (float*)d_ws;
    float* e         = (float*)((char*)d_ws + off_e);

    if (ws_size >= need) {
        short*  encb = (short*)((char*)d_ws + off_encb);
        short*  whb  = (short*)((char*)d_ws + off_whb);
        float*  part = (float*)((char*)d_ws + off_part);
        float2* pm   = (float2*)((char*)d_ws + off_pm);
        prep_cvt_kernel<<<10256, 256, 0, stream>>>(dec, Ws, bs, enc, Wh,
                                                   dec_feats, encb, whb);
        score_mfma8_kernel<<<512, 512, 0, stream>>>(
            encb, whb, bh, dec_feats, cov, wc, v, lens, e, pm);
        context_part_kernel<<<dim3(SCH, B), 256, 0, stream>>>(
            e, lens, pm, cov, encb, attn, cov_out, part);
        context_reduce_kernel<<<(B * N) / 256, 256, 0, stream>>>(part, ctx);
    } else {
        prep_kernel<<<8192, 256, 0, stream>>>(dec, Ws, bs, dec_feats, e);
        hipMemsetAsync(ctx, 0, (size_t)B * N * sizeof(float), stream);
        score_mfma_kernel<<<(B * S / BR) * (N / BM), 256, 0, stream>>>(
            enc, Wh, bh, dec_feats, cov, wc, v, e);
        softmax_kernel<<<B, 1024, 0, stream>>>(e, lens, cov, attn, cov_out);
        context_kernel<<<dim3(SCH, B), 256, 0, stream>>>(attn, enc, ctx);
    }
}